// Round 1
// baseline (339.712 us; speedup 1.0000x reference)
//
#include <hip/hip_runtime.h>
#include <math.h>

#define NN 512   // rows of feat_x / set size
#define IN 512   // INPUT_DIM
#define HD 256   // HIDDEN_DIM
#define RD 256   // REP_DIM
#define SH 128   // SCORE_HIDDEN

__device__ __forceinline__ float gelu_exact(float x){
    return 0.5f * x * (1.0f + erff(x * 0.7071067811865475f));
}

// K1: r = GELU(feat @ g_w1 + b1) @ g_w2 + b2 for x,pos,neg. 8 rows/block.
// Also writes transposed copies of r_p, r_n for coalesced Gram in K3.
__global__ __launch_bounds__(256) void k_reps(
    const float* __restrict__ fx, const float* __restrict__ fp, const float* __restrict__ fn,
    const float* __restrict__ w1, const float* __restrict__ b1,
    const float* __restrict__ w2, const float* __restrict__ b2,
    float* __restrict__ r_x, float* __restrict__ r_p, float* __restrict__ r_n,
    float* __restrict__ r_pT, float* __restrict__ r_nT)
{
    __shared__ float xs[8][IN];
    __shared__ float hs[8][HD];
    const int t = threadIdx.x;
    const int mat = blockIdx.x >> 6;
    const int row0 = (blockIdx.x & 63) << 3;
    const float* src = (mat==0) ? fx : (mat==1) ? fp : fn;
    #pragma unroll
    for (int j=0;j<8;j++){
        xs[j][t]     = src[(row0+j)*IN + t];
        xs[j][t+256] = src[(row0+j)*IN + t + 256];
    }
    __syncthreads();
    const float bb = b1[t];
    float acc[8];
    #pragma unroll
    for (int j=0;j<8;j++) acc[j]=bb;
    for (int i=0;i<IN;i++){
        const float w = w1[i*HD + t];
        #pragma unroll
        for (int j=0;j<8;j++) acc[j] = fmaf(xs[j][i], w, acc[j]);
    }
    #pragma unroll
    for (int j=0;j<8;j++) hs[j][t] = gelu_exact(acc[j]);
    __syncthreads();
    const float bb2 = b2[t];
    float acc2[8];
    #pragma unroll
    for (int j=0;j<8;j++) acc2[j]=bb2;
    for (int k=0;k<HD;k++){
        const float w = w2[k*RD + t];
        #pragma unroll
        for (int j=0;j<8;j++) acc2[j] = fmaf(hs[j][k], w, acc2[j]);
    }
    float* rout = (mat==0) ? r_x : (mat==1) ? r_p : r_n;
    #pragma unroll
    for (int j=0;j<8;j++) rout[(row0+j)*RD + t] = acc2[j];
    if (mat){
        float* rT = (mat==1) ? r_pT : r_nT;
        #pragma unroll
        for (int j=0;j<8;j++) rT[t*NN + row0 + j] = acc2[j];
    }
}

// K2: A_x[n][k] = r_x[n]@(s_w1[0:256]-s_w1[512:768]);
//     BT_y[k][m] = r_y[m]@(s_w1[256:512]+s_w1[512:768]) (transposed store);
//     plus squared row norms. 8 rows/block, 128 threads.
__global__ __launch_bounds__(128) void k_ab(
    const float* __restrict__ r_x, const float* __restrict__ r_p, const float* __restrict__ r_n,
    const float* __restrict__ s_w1,
    float* __restrict__ A_x, float* __restrict__ BT_p, float* __restrict__ BT_n,
    float* __restrict__ nx2, float* __restrict__ np2, float* __restrict__ nn2)
{
    __shared__ float xs[8][RD];
    __shared__ float red[8][2];
    const int t = threadIdx.x;  // 128
    const int mat = blockIdx.x >> 6;
    const int row0 = (blockIdx.x & 63) << 3;
    const float* src = (mat==0) ? r_x : (mat==1) ? r_p : r_n;
    #pragma unroll
    for (int j=0;j<8;j++){
        xs[j][t]     = src[(row0+j)*RD + t];
        xs[j][t+128] = src[(row0+j)*RD + t + 128];
    }
    __syncthreads();
    float acc[8] = {0,0,0,0,0,0,0,0};
    for (int i=0;i<RD;i++){
        float w;
        if (mat==0) w = s_w1[i*SH + t]       - s_w1[(512+i)*SH + t];
        else        w = s_w1[(256+i)*SH + t] + s_w1[(512+i)*SH + t];
        #pragma unroll
        for (int j=0;j<8;j++) acc[j] = fmaf(xs[j][i], w, acc[j]);
    }
    if (mat==0){
        #pragma unroll
        for (int j=0;j<8;j++) A_x[(row0+j)*SH + t] = acc[j];
    } else {
        float* BT = (mat==1) ? BT_p : BT_n;
        #pragma unroll
        for (int j=0;j<8;j++) BT[t*NN + row0 + j] = acc[j];
    }
    float* nrm = (mat==0) ? nx2 : (mat==1) ? np2 : nn2;
    const int lane = t & 63, wv = t >> 6;
    #pragma unroll
    for (int j=0;j<8;j++){
        float v = xs[j][t]*xs[j][t] + xs[j][t+128]*xs[j][t+128];
        #pragma unroll
        for (int off=32; off>=1; off>>=1) v += __shfl_xor(v, off);
        if (lane==0) red[j][wv] = v;
    }
    __syncthreads();
    if (t < 8) nrm[row0 + t] = red[t][0] + red[t][1];
}

// K3: D[n][m] = sqrt(max(0, ||x_n||^2 + ||y_m||^2 - 2 x_n.y_m)). 4 n-rows/block.
__global__ __launch_bounds__(256) void k_dist(
    const float* __restrict__ r_x, const float* __restrict__ r_pT, const float* __restrict__ r_nT,
    const float* __restrict__ nx2, const float* __restrict__ np2, const float* __restrict__ nn2,
    float* __restrict__ D_p, float* __restrict__ D_n)
{
    __shared__ float xs[4][RD];
    const int t = threadIdx.x;
    const int s = blockIdx.x >> 7;
    const int n0 = (blockIdx.x & 127) << 2;
    const float* yT  = s ? r_nT : r_pT;
    const float* ny2 = s ? nn2 : np2;
    float* D = s ? D_n : D_p;
    #pragma unroll
    for (int j=0;j<4;j++) xs[j][t] = r_x[(n0+j)*RD + t];
    __syncthreads();
    const int m0 = t, m1 = t + 256;
    float a0[4]={0,0,0,0}, a1[4]={0,0,0,0};
    for (int r=0;r<RD;r++){
        const float y0 = yT[r*NN + m0];
        const float y1 = yT[r*NN + m1];
        #pragma unroll
        for (int j=0;j<4;j++){
            a0[j] = fmaf(xs[j][r], y0, a0[j]);
            a1[j] = fmaf(xs[j][r], y1, a1[j]);
        }
    }
    const float b0 = ny2[m0], b1v = ny2[m1];
    #pragma unroll
    for (int j=0;j<4;j++){
        const float a = nx2[n0+j];
        D[(n0+j)*NN + m0] = sqrtf(fmaxf(a + b0  - 2.0f*a0[j], 0.0f));
        D[(n0+j)*NN + m1] = sqrtf(fmaf(-2.0f, a1[j], a + b1v) > 0.0f ? fmaf(-2.0f, a1[j], a + b1v) : 0.0f);
    }
}

// K4: logits -> softmax weights per (set, n). The hot kernel.
__global__ __launch_bounds__(256) void k_scores(
    const float* __restrict__ A_x, const float* __restrict__ BT_p, const float* __restrict__ BT_n,
    const float* __restrict__ D_p, const float* __restrict__ D_n,
    const float* __restrict__ s_w1, const float* __restrict__ s_b1,
    const float* __restrict__ s_w2, const float* __restrict__ s_b2,
    float* __restrict__ W_p, float* __restrict__ W_n)
{
    __shared__ float ab[SH], wnv[SH], w2v[SH];
    __shared__ float red[256];
    const int t = threadIdx.x;
    const int s = blockIdx.x >> 9;
    const int n = blockIdx.x & 511;
    const float* BT = s ? BT_n : BT_p;
    const float* D  = s ? D_n : D_p;
    float* W = s ? W_n : W_p;
    if (t < SH){
        ab[t]  = A_x[n*SH + t] + s_b1[t];
        wnv[t] = s_w1[768*SH + t];
        w2v[t] = s_w2[t];
    }
    __syncthreads();
    const int m0 = t, m1 = t + 256;
    const float dn0 = D[n*NN + m0], dn1 = D[n*NN + m1];
    float acc0 = 0.f, acc1 = 0.f;
    for (int k=0;k<SH;k++){
        const float a = ab[k], w = wnv[k], o = w2v[k];
        const float p0 = fmaf(dn0, w, a + BT[k*NN + m0]);
        const float p1 = fmaf(dn1, w, a + BT[k*NN + m1]);
        acc0 = fmaf(o, gelu_exact(p0), acc0);
        acc1 = fmaf(o, gelu_exact(p1), acc1);
    }
    const float b2v = s_b2[0];
    const float l0 = acc0 + b2v, l1 = acc1 + b2v;
    red[t] = fmaxf(l0, l1);
    __syncthreads();
    for (int sd=128; sd>0; sd>>=1){
        if (t < sd) red[t] = fmaxf(red[t], red[t+sd]);
        __syncthreads();
    }
    const float mx = red[0];
    __syncthreads();
    const float e0 = expf(l0 - mx), e1 = expf(l1 - mx);
    red[t] = e0 + e1;
    __syncthreads();
    for (int sd=128; sd>0; sd>>=1){
        if (t < sd) red[t] += red[t+sd];
        __syncthreads();
    }
    const float inv = 1.0f / red[0];
    W[n*NN + m0] = e0 * inv;
    W[n*NN + m1] = e1 * inv;
}

// K5: out[n] = (W_p[n]@r_p - W_n[n]@r_n) @ out_w   (x_rep term cancels). 4 n/block.
__global__ __launch_bounds__(256) void k_final(
    const float* __restrict__ W_p, const float* __restrict__ W_n,
    const float* __restrict__ r_p, const float* __restrict__ r_n,
    const float* __restrict__ out_w, float* __restrict__ out)
{
    __shared__ float wp[4][NN];
    __shared__ float wq[4][NN];
    __shared__ float dval[4][RD];
    const int t = threadIdx.x;
    const int n0 = blockIdx.x << 2;
    #pragma unroll
    for (int j=0;j<4;j++){
        wp[j][t]     = W_p[(n0+j)*NN + t];
        wp[j][t+256] = W_p[(n0+j)*NN + t + 256];
        wq[j][t]     = W_n[(n0+j)*NN + t];
        wq[j][t+256] = W_n[(n0+j)*NN + t + 256];
    }
    __syncthreads();
    float acc[4] = {0,0,0,0};
    for (int m=0;m<NN;m++){
        const float yp = r_p[m*RD + t];
        const float yn = -r_n[m*RD + t];
        #pragma unroll
        for (int j=0;j<4;j++){
            acc[j] = fmaf(wp[j][m], yp, acc[j]);
            acc[j] = fmaf(wq[j][m], yn, acc[j]);
        }
    }
    #pragma unroll
    for (int j=0;j<4;j++) dval[j][t] = acc[j];
    __syncthreads();
    float o0[4] = {0,0,0,0}, o1[4] = {0,0,0,0};
    for (int r=0;r<RD;r++){
        const float w0 = out_w[r*IN + t];
        const float w1 = out_w[r*IN + t + 256];
        #pragma unroll
        for (int j=0;j<4;j++){
            o0[j] = fmaf(dval[j][r], w0, o0[j]);
            o1[j] = fmaf(dval[j][r], w1, o1[j]);
        }
    }
    #pragma unroll
    for (int j=0;j<4;j++){
        out[(n0+j)*IN + t]       = o0[j];
        out[(n0+j)*IN + t + 256] = o1[j];
    }
}

extern "C" void kernel_launch(void* const* d_in, const int* in_sizes, int n_in,
                              void* d_out, int out_size, void* d_ws, size_t ws_size,
                              hipStream_t stream)
{
    const float* fx  = (const float*)d_in[0];
    const float* fp  = (const float*)d_in[1];
    const float* fn  = (const float*)d_in[2];
    const float* gw1 = (const float*)d_in[3];
    const float* gb1 = (const float*)d_in[4];
    const float* gw2 = (const float*)d_in[5];
    const float* gb2 = (const float*)d_in[6];
    const float* ow  = (const float*)d_in[7];
    const float* sw1 = (const float*)d_in[8];
    const float* sb1 = (const float*)d_in[9];
    const float* sw2 = (const float*)d_in[10];
    const float* sb2 = (const float*)d_in[11];
    float* out = (float*)d_out;

    float* ws   = (float*)d_ws;
    float* r_x  = ws;               // 512*256
    float* r_p  = r_x  + 131072;
    float* r_n  = r_p  + 131072;
    float* r_pT = r_n  + 131072;    // 256*512
    float* r_nT = r_pT + 131072;
    float* A_x  = r_nT + 131072;    // 512*128
    float* BT_p = A_x  + 65536;     // 128*512
    float* BT_n = BT_p + 65536;
    float* nx2  = BT_n + 65536;     // 512
    float* np2  = nx2  + 512;
    float* nn2  = np2  + 512;
    float* D_p  = nn2  + 512;       // 512*512
    float* D_n  = D_p  + 262144;
    float* W_p  = D_n  + 262144;
    float* W_n  = W_p  + 262144;    // total ~7.6 MB

    hipLaunchKernelGGL(k_reps, dim3(192), dim3(256), 0, stream,
                       fx, fp, fn, gw1, gb1, gw2, gb2, r_x, r_p, r_n, r_pT, r_nT);
    hipLaunchKernelGGL(k_ab, dim3(192), dim3(128), 0, stream,
                       r_x, r_p, r_n, sw1, A_x, BT_p, BT_n, nx2, np2, nn2);
    hipLaunchKernelGGL(k_dist, dim3(256), dim3(256), 0, stream,
                       r_x, r_pT, r_nT, nx2, np2, nn2, D_p, D_n);
    hipLaunchKernelGGL(k_scores, dim3(1024), dim3(256), 0, stream,
                       A_x, BT_p, BT_n, D_p, D_n, sw1, sb1, sw2, sb2, W_p, W_n);
    hipLaunchKernelGGL(k_final, dim3(128), dim3(256), 0, stream,
                       W_p, W_n, r_p, r_n, ow, out);
}

// Round 2
// 203.370 us; speedup vs baseline: 1.6704x; 1.6704x over previous
//
#include <hip/hip_runtime.h>
#include <math.h>

#define NN 512   // set size / rows of feat_x
#define IN 512   // INPUT_DIM
#define HD 256   // HIDDEN_DIM
#define RD 256   // REP_DIM
#define SH 128   // SCORE_HIDDEN

__device__ __forceinline__ float gelu_exact(float x){
    return 0.5f * x * (1.0f + erff(x * 0.7071067811865475f));
}

// K1: rep = GELU(feat @ g_w1 + b1) @ g_w2 + b2 for x,pos,neg.
// 4 rows/block, 256 threads = 64 colgroups(x4 cols) x 4 K-slices; LDS tree-reduce.
__global__ __launch_bounds__(256) void k_reps(
    const float* __restrict__ fx, const float* __restrict__ fp, const float* __restrict__ fn,
    const float* __restrict__ w1, const float* __restrict__ b1,
    const float* __restrict__ w2, const float* __restrict__ b2,
    float* __restrict__ r_x, float* __restrict__ r_p, float* __restrict__ r_n,
    float* __restrict__ r_pT, float* __restrict__ r_nT)
{
    __shared__ float xs[4][IN];      // 8 KB
    __shared__ float ps[16][HD];     // [s*4+j][c] 16 KB
    __shared__ float hs[4][HD];      // 4 KB
    const int t = threadIdx.x;
    const int mat = blockIdx.x >> 7;            // 3 mats x 128 rowgroups
    const int row0 = (blockIdx.x & 127) << 2;
    const float* src = (mat==0) ? fx : (mat==1) ? fp : fn;

    #pragma unroll
    for (int rep=0; rep<2; rep++){
        int f = rep*256 + t;                    // float4 index in [0,512)
        int j = f >> 7, c4 = (f & 127) << 2;
        *(float4*)&xs[j][c4] = *(const float4*)&src[(row0+j)*IN + c4];
    }
    __syncthreads();

    const int cg = t & 63, s = t >> 6;          // 4 K-slices
    const int c0 = cg << 2;
    float4 acc[4];
    #pragma unroll
    for (int j=0;j<4;j++) acc[j] = make_float4(0.f,0.f,0.f,0.f);

    // GEMM1: K=512, this slice covers i in [s*128, s*128+128)
    const float* wp1 = w1 + (s*128)*HD + c0;
    for (int ii=0; ii<128; ii++){
        float4 w = *(const float4*)wp1; wp1 += HD;
        const int i = s*128 + ii;
        #pragma unroll
        for (int j=0;j<4;j++){
            const float xv = xs[j][i];
            acc[j].x = fmaf(xv, w.x, acc[j].x);
            acc[j].y = fmaf(xv, w.y, acc[j].y);
            acc[j].z = fmaf(xv, w.z, acc[j].z);
            acc[j].w = fmaf(xv, w.w, acc[j].w);
        }
    }
    #pragma unroll
    for (int j=0;j<4;j++) *(float4*)&ps[s*4+j][c0] = acc[j];
    __syncthreads();

    // reduce 4 partials + bias + GELU -> hs
    #pragma unroll
    for (int j=0;j<4;j++){
        float v = ps[j][t] + ps[4+j][t] + ps[8+j][t] + ps[12+j][t];
        hs[j][t] = gelu_exact(v + b1[t]);
    }
    __syncthreads();

    // GEMM2: K=256, slice i in [s*64, s*64+64)
    #pragma unroll
    for (int j=0;j<4;j++) acc[j] = make_float4(0.f,0.f,0.f,0.f);
    const float* wp2 = w2 + (s*64)*RD + c0;
    for (int ii=0; ii<64; ii++){
        float4 w = *(const float4*)wp2; wp2 += RD;
        const int i = s*64 + ii;
        #pragma unroll
        for (int j=0;j<4;j++){
            const float xv = hs[j][i];
            acc[j].x = fmaf(xv, w.x, acc[j].x);
            acc[j].y = fmaf(xv, w.y, acc[j].y);
            acc[j].z = fmaf(xv, w.z, acc[j].z);
            acc[j].w = fmaf(xv, w.w, acc[j].w);
        }
    }
    #pragma unroll
    for (int j=0;j<4;j++) *(float4*)&ps[s*4+j][c0] = acc[j];
    __syncthreads();

    float* rout = (mat==0) ? r_x : (mat==1) ? r_p : r_n;
    float* rT   = (mat==1) ? r_pT : r_nT;
    #pragma unroll
    for (int j=0;j<4;j++){
        float v = ps[j][t] + ps[4+j][t] + ps[8+j][t] + ps[12+j][t] + b2[t];
        rout[(row0+j)*RD + t] = v;
        if (mat) rT[t*NN + row0 + j] = v;
    }
}

// K2: A_x = r_x @ (s_w1[0:256]-s_w1[512:768]);  BT_y = ((s_w1[256:512]+s_w1[512:768])^T @ r_y^T)
// stored transposed; plus squared row norms. 4 rows/block, 256 thr = 32 colgroups x 8 K-slices.
__global__ __launch_bounds__(256) void k_ab(
    const float* __restrict__ r_x, const float* __restrict__ r_p, const float* __restrict__ r_n,
    const float* __restrict__ s_w1,
    float* __restrict__ A_x, float* __restrict__ BT_p, float* __restrict__ BT_n,
    float* __restrict__ nx2, float* __restrict__ np2, float* __restrict__ nn2)
{
    __shared__ float xs[4][RD];       // 4 KB
    __shared__ float ps[32][SH];      // [s*4+j][c] 16 KB
    __shared__ float red2[4][4];
    const int t = threadIdx.x;
    const int mat = blockIdx.x >> 7;
    const int row0 = (blockIdx.x & 127) << 2;
    const float* src = (mat==0) ? r_x : (mat==1) ? r_p : r_n;
    {
        int j = t >> 6, c4 = (t & 63) << 2;   // 256 float4s = 4x256 floats
        *(float4*)&xs[j][c4] = *(const float4*)&src[(row0+j)*RD + c4];
    }
    __syncthreads();

    const int cg = t & 31, s = t >> 5;        // 8 K-slices
    const int c0 = cg << 2;
    float4 acc[4];
    #pragma unroll
    for (int j=0;j<4;j++) acc[j] = make_float4(0.f,0.f,0.f,0.f);

    const float sgn = (mat==0) ? -1.0f : 1.0f;
    const int base1 = (mat==0) ? 0 : 256;
    const float* p1 = s_w1 + (base1 + s*32)*SH + c0;
    const float* p3 = s_w1 + (512   + s*32)*SH + c0;
    for (int ii=0; ii<32; ii++){
        float4 wa = *(const float4*)p1; p1 += SH;
        float4 wd = *(const float4*)p3; p3 += SH;
        float4 w;
        w.x = fmaf(sgn, wd.x, wa.x);
        w.y = fmaf(sgn, wd.y, wa.y);
        w.z = fmaf(sgn, wd.z, wa.z);
        w.w = fmaf(sgn, wd.w, wa.w);
        const int i = s*32 + ii;
        #pragma unroll
        for (int j=0;j<4;j++){
            const float xv = xs[j][i];
            acc[j].x = fmaf(xv, w.x, acc[j].x);
            acc[j].y = fmaf(xv, w.y, acc[j].y);
            acc[j].z = fmaf(xv, w.z, acc[j].z);
            acc[j].w = fmaf(xv, w.w, acc[j].w);
        }
    }
    #pragma unroll
    for (int j=0;j<4;j++) *(float4*)&ps[s*4+j][c0] = acc[j];
    __syncthreads();

    {   // reduce 8 partials; outputs 4 rows x 128 cols, 2 per thread
        const int c = t & 127, jb = (t >> 7) << 1;
        #pragma unroll
        for (int q=0;q<2;q++){
            const int j = jb + q;
            float v = 0.f;
            #pragma unroll
            for (int ss=0; ss<8; ss++) v += ps[ss*4+j][c];
            if (mat==0) A_x[(row0+j)*SH + c] = v;
            else ((mat==1) ? BT_p : BT_n)[c*NN + row0 + j] = v;
        }
    }

    // squared row norms of the 4 rep rows
    const int lane = t & 63, wv = t >> 6;
    #pragma unroll
    for (int j=0;j<4;j++){
        float v = xs[j][t] * xs[j][t];
        #pragma unroll
        for (int off=32; off>=1; off>>=1) v += __shfl_xor(v, off);
        if (lane==0) red2[j][wv] = v;
    }
    __syncthreads();
    if (t < 4){
        float* nrm = (mat==0) ? nx2 : (mat==1) ? np2 : nn2;
        nrm[row0+t] = red2[t][0] + red2[t][1] + red2[t][2] + red2[t][3];
    }
}

// K3 (fused dist+scores+softmax): one block per (set, n). Thread t owns m=2t,2t+1.
// Distance via Gram identity computed in-register; logits via decomposed score net.
__global__ __launch_bounds__(256) void k_sd(
    const float* __restrict__ r_x, const float* __restrict__ r_pT, const float* __restrict__ r_nT,
    const float* __restrict__ A_x, const float* __restrict__ BT_p, const float* __restrict__ BT_n,
    const float* __restrict__ nx2, const float* __restrict__ np2, const float* __restrict__ nn2,
    const float* __restrict__ s_w1, const float* __restrict__ s_b1,
    const float* __restrict__ s_w2, const float* __restrict__ s_b2,
    float* __restrict__ W_p, float* __restrict__ W_n)
{
    __shared__ float xr[RD];
    __shared__ float abv[SH], wnv[SH], w2v[SH];
    __shared__ float red[256];
    const int t = threadIdx.x;
    const int set = blockIdx.x >> 9;
    const int n = blockIdx.x & 511;
    const float* yT  = set ? r_nT : r_pT;
    const float* BT  = set ? BT_n : BT_p;
    const float* ny2 = set ? nn2 : np2;
    float* W = set ? W_n : W_p;

    xr[t] = r_x[n*RD + t];
    if (t < SH){
        abv[t] = A_x[n*SH + t] + s_b1[t];
        wnv[t] = s_w1[768*SH + t];
        w2v[t] = s_w2[t];
    }
    __syncthreads();

    const int m0 = t << 1;
    // phase 1: dot(x_n, y_m) for m0, m0+1
    float dx = 0.f, dy = 0.f;
    const float* yp = yT + m0;
    for (int r=0; r<RD; r++){
        float2 y = *(const float2*)yp; yp += NN;
        const float xv = xr[r];
        dx = fmaf(xv, y.x, dx);
        dy = fmaf(xv, y.y, dy);
    }
    const float2 n2 = *(const float2*)&ny2[m0];
    const float nx = nx2[n];
    const float dn0 = sqrtf(fmaxf(fmaf(-2.f, dx, nx + n2.x), 0.f));
    const float dn1 = sqrtf(fmaxf(fmaf(-2.f, dy, nx + n2.y), 0.f));

    // phase 2: logits
    float acc0 = 0.f, acc1 = 0.f;
    const float* bp = BT + m0;
    for (int k=0; k<SH; k++){
        float2 b = *(const float2*)bp; bp += NN;
        const float a = abv[k], wn = wnv[k], o = w2v[k];
        acc0 = fmaf(o, gelu_exact(fmaf(dn0, wn, a + b.x)), acc0);
        acc1 = fmaf(o, gelu_exact(fmaf(dn1, wn, a + b.y)), acc1);
    }
    const float b2v = s_b2[0];
    const float l0 = acc0 + b2v, l1 = acc1 + b2v;

    // softmax over 512 m
    red[t] = fmaxf(l0, l1);
    __syncthreads();
    for (int sd=128; sd>0; sd>>=1){
        if (t < sd) red[t] = fmaxf(red[t], red[t+sd]);
        __syncthreads();
    }
    const float mx = red[0];
    __syncthreads();
    const float e0 = expf(l0 - mx), e1 = expf(l1 - mx);
    red[t] = e0 + e1;
    __syncthreads();
    for (int sd=128; sd>0; sd>>=1){
        if (t < sd) red[t] += red[t+sd];
        __syncthreads();
    }
    const float inv = 1.0f / red[0];
    *(float2*)&W[n*NN + m0] = make_float2(e0*inv, e1*inv);
}

// K4: out[n] = (W_p[n]@r_p - W_n[n]@r_n) @ out_w   (x_rep term cancels pos-neg).
// 2 rows/block, 512 threads, K-split + LDS reduce in both phases.
__global__ __launch_bounds__(512) void k_final(
    const float* __restrict__ W_p, const float* __restrict__ W_n,
    const float* __restrict__ r_p, const float* __restrict__ r_n,
    const float* __restrict__ out_w, float* __restrict__ out)
{
    __shared__ float wp[2][NN];    // 4 KB
    __shared__ float wq[2][NN];    // 4 KB
    __shared__ float psA[16][RD];  // [s*2+j][c] 16 KB
    __shared__ float dv[2][RD];    // 2 KB
    __shared__ float ps2[8][NN];   // [s*2+j][c] 16 KB
    const int t = threadIdx.x;
    const int n0 = blockIdx.x << 1;

    {   // stage weights rows: 512 float4s = 2048 floats
        const int j = (t >> 7) & 1, c4 = (t & 127) << 2;
        if (t < 256) *(float4*)&wp[j][c4] = *(const float4*)&W_p[(n0+j)*NN + c4];
        else         *(float4*)&wq[j][c4] = *(const float4*)&W_n[(n0+j)*NN + c4];
    }
    __syncthreads();

    {   // phase A: dv[j][c] = sum_m wp[j][m]*r_p[m][c] - wq[j][m]*r_n[m][c]
        const int cg = t & 63, s = t >> 6;   // 8 K-slices over m
        const int c0 = cg << 2;
        float4 a0 = make_float4(0.f,0.f,0.f,0.f), a1 = a0;
        const float* pp = r_p + (s*64)*RD + c0;
        const float* pn = r_n + (s*64)*RD + c0;
        for (int mm=0; mm<64; mm++){
            float4 yp4 = *(const float4*)pp; pp += RD;
            float4 yn4 = *(const float4*)pn; pn += RD;
            const int m = s*64 + mm;
            const float w0 = wp[0][m], w1v = wp[1][m];
            const float q0 = wq[0][m], q1v = wq[1][m];
            a0.x = fmaf(w0, yp4.x, a0.x); a0.x = fmaf(-q0, yn4.x, a0.x);
            a0.y = fmaf(w0, yp4.y, a0.y); a0.y = fmaf(-q0, yn4.y, a0.y);
            a0.z = fmaf(w0, yp4.z, a0.z); a0.z = fmaf(-q0, yn4.z, a0.z);
            a0.w = fmaf(w0, yp4.w, a0.w); a0.w = fmaf(-q0, yn4.w, a0.w);
            a1.x = fmaf(w1v, yp4.x, a1.x); a1.x = fmaf(-q1v, yn4.x, a1.x);
            a1.y = fmaf(w1v, yp4.y, a1.y); a1.y = fmaf(-q1v, yn4.y, a1.y);
            a1.z = fmaf(w1v, yp4.z, a1.z); a1.z = fmaf(-q1v, yn4.z, a1.z);
            a1.w = fmaf(w1v, yp4.w, a1.w); a1.w = fmaf(-q1v, yn4.w, a1.w);
        }
        *(float4*)&psA[s*2+0][c0] = a0;
        *(float4*)&psA[s*2+1][c0] = a1;
    }
    __syncthreads();

    {   // reduce A: 2x256 outputs
        const int j = t >> 8, c = t & 255;
        float v = 0.f;
        #pragma unroll
        for (int ss=0; ss<8; ss++) v += psA[ss*2+j][c];
        dv[j][c] = v;
    }
    __syncthreads();

    {   // phase B: out[j][c] = sum_r dv[j][r]*out_w[r][c], c<512
        const int og = t & 127, s = t >> 7;  // 4 K-slices over r
        const int c0 = og << 2;
        float4 a0 = make_float4(0.f,0.f,0.f,0.f), a1 = a0;
        const float* wo = out_w + (s*64)*IN + c0;
        for (int rr=0; rr<64; rr++){
            float4 w = *(const float4*)wo; wo += IN;
            const int r = s*64 + rr;
            const float d0 = dv[0][r], d1 = dv[1][r];
            a0.x = fmaf(d0, w.x, a0.x); a0.y = fmaf(d0, w.y, a0.y);
            a0.z = fmaf(d0, w.z, a0.z); a0.w = fmaf(d0, w.w, a0.w);
            a1.x = fmaf(d1, w.x, a1.x); a1.y = fmaf(d1, w.y, a1.y);
            a1.z = fmaf(d1, w.z, a1.z); a1.w = fmaf(d1, w.w, a1.w);
        }
        *(float4*)&ps2[s*2+0][c0] = a0;
        *(float4*)&ps2[s*2+1][c0] = a1;
    }
    __syncthreads();

    {   // reduce B + store: 2x512 outputs
        const int c = t;
        #pragma unroll
        for (int j=0;j<2;j++){
            float v = 0.f;
            #pragma unroll
            for (int ss=0; ss<4; ss++) v += ps2[ss*2+j][c];
            out[(n0+j)*IN + c] = v;
        }
    }
}

extern "C" void kernel_launch(void* const* d_in, const int* in_sizes, int n_in,
                              void* d_out, int out_size, void* d_ws, size_t ws_size,
                              hipStream_t stream)
{
    const float* fx  = (const float*)d_in[0];
    const float* fp  = (const float*)d_in[1];
    const float* fn  = (const float*)d_in[2];
    const float* gw1 = (const float*)d_in[3];
    const float* gb1 = (const float*)d_in[4];
    const float* gw2 = (const float*)d_in[5];
    const float* gb2 = (const float*)d_in[6];
    const float* ow  = (const float*)d_in[7];
    const float* sw1 = (const float*)d_in[8];
    const float* sb1 = (const float*)d_in[9];
    const float* sw2 = (const float*)d_in[10];
    const float* sb2 = (const float*)d_in[11];
    float* out = (float*)d_out;

    float* ws   = (float*)d_ws;
    float* r_x  = ws;               // 512*256
    float* r_p  = r_x  + 131072;
    float* r_n  = r_p  + 131072;
    float* r_pT = r_n  + 131072;    // 256*512
    float* r_nT = r_pT + 131072;
    float* A_x  = r_nT + 131072;    // 512*128
    float* BT_p = A_x  + 65536;     // 128*512
    float* BT_n = BT_p + 65536;
    float* nx2  = BT_n + 65536;     // 512
    float* np2  = nx2  + 512;
    float* nn2  = np2  + 512;
    float* W_p  = nn2  + 512;       // 512*512
    float* W_n  = W_p  + 262144;

    hipLaunchKernelGGL(k_reps, dim3(384), dim3(256), 0, stream,
                       fx, fp, fn, gw1, gb1, gw2, gb2, r_x, r_p, r_n, r_pT, r_nT);
    hipLaunchKernelGGL(k_ab, dim3(384), dim3(256), 0, stream,
                       r_x, r_p, r_n, sw1, A_x, BT_p, BT_n, nx2, np2, nn2);
    hipLaunchKernelGGL(k_sd, dim3(1024), dim3(256), 0, stream,
                       r_x, r_pT, r_nT, A_x, BT_p, BT_n, nx2, np2, nn2,
                       sw1, sb1, sw2, sb2, W_p, W_n);
    hipLaunchKernelGGL(k_final, dim3(256), dim3(512), 0, stream,
                       W_p, W_n, r_p, r_n, ow, out);
}

// Round 3
// 183.431 us; speedup vs baseline: 1.8520x; 1.1087x over previous
//
#include <hip/hip_runtime.h>
#include <math.h>

#define NN 512   // set size / rows of feat_x
#define IN 512   // INPUT_DIM
#define HD 256   // HIDDEN_DIM
#define RD 256   // REP_DIM
#define SH 128   // SCORE_HIDDEN

// Branchless erf-GELU, Abramowitz-Stegun 7.1.26 (|erf err| <= 1.5e-7).
// ~12 VALU + v_rcp + v_exp vs libm erff's ~50-120 ops with divergent branches.
__device__ __forceinline__ float gelu_fast(float x){
    const float z  = x * 0.70710678118654752f;
    const float az = fabsf(z);
    const float t  = __builtin_amdgcn_rcpf(fmaf(0.3275911f, az, 1.0f));
    float p = fmaf(1.061405429f, t, -1.453152027f);
    p = fmaf(p, t, 1.421413741f);
    p = fmaf(p, t, -0.284496736f);
    p = fmaf(p, t, 0.254829592f);
    p = p * t;
    const float e = __builtin_amdgcn_exp2f(z * z * -1.4426950408889634f);
    const float E = p * e;                        // erfc(|z|)
    const float one_plus_erf = (x >= 0.0f) ? (2.0f - E) : E;
    return 0.5f * x * one_plus_erf;
}

// K_G1: h = GELU(feat @ g_w1 + b1), feat = [x;pos;neg] stacked (1536 x 512).
// Block: 4 rows x 128 cols, 8 K-slices. 768 blocks = 3/CU.
__global__ __launch_bounds__(256) void k_g1(
    const float* __restrict__ fx, const float* __restrict__ fp, const float* __restrict__ fn,
    const float* __restrict__ w1, const float* __restrict__ b1,
    float* __restrict__ h)
{
    __shared__ float xs[4][IN];      // 8 KB
    __shared__ float ps[32][128];    // [s*4+j][c] 16 KB
    const int t = threadIdx.x;
    const int mat = blockIdx.x >> 8;
    const int rem = blockIdx.x & 255;
    const int row0 = (rem >> 1) << 2;
    const int colbase = (rem & 1) << 7;
    const float* src = (mat==0) ? fx : (mat==1) ? fp : fn;

    #pragma unroll
    for (int rep=0; rep<2; rep++){
        int f = rep*256 + t;
        int j = f >> 7, c4 = (f & 127) << 2;
        *(float4*)&xs[j][c4] = *(const float4*)&src[(row0+j)*IN + c4];
    }
    __syncthreads();

    const int cg = t & 31, s = t >> 5;
    const int c0 = cg << 2;
    float4 acc[4];
    #pragma unroll
    for (int j=0;j<4;j++) acc[j] = make_float4(0.f,0.f,0.f,0.f);

    const float* wp = w1 + (s*64)*HD + colbase + c0;
    #pragma unroll 4
    for (int ii=0; ii<64; ii++){
        float4 w = *(const float4*)wp; wp += HD;
        const int i = s*64 + ii;
        #pragma unroll
        for (int j=0;j<4;j++){
            const float xv = xs[j][i];
            acc[j].x = fmaf(xv, w.x, acc[j].x);
            acc[j].y = fmaf(xv, w.y, acc[j].y);
            acc[j].z = fmaf(xv, w.z, acc[j].z);
            acc[j].w = fmaf(xv, w.w, acc[j].w);
        }
    }
    #pragma unroll
    for (int j=0;j<4;j++) *(float4*)&ps[s*4+j][c0] = acc[j];
    __syncthreads();

    #pragma unroll
    for (int rep=0; rep<2; rep++){
        const int idx = rep*256 + t;
        const int j = idx >> 7, c = idx & 127;
        float v = 0.f;
        #pragma unroll
        for (int ss=0; ss<8; ss++) v += ps[ss*4+j][c];
        h[(mat*NN + row0 + j)*HD + colbase + c] = gelu_fast(v + b1[colbase + c]);
    }
}

// K_G2: rep = h @ g_w2 + b2 (1536 x 256), plus transposed copies for pos/neg.
__global__ __launch_bounds__(256) void k_g2(
    const float* __restrict__ h,
    const float* __restrict__ w2, const float* __restrict__ b2,
    float* __restrict__ r_x, float* __restrict__ r_p, float* __restrict__ r_n,
    float* __restrict__ r_pT, float* __restrict__ r_nT)
{
    __shared__ float xs[4][HD];      // 4 KB
    __shared__ float ps[32][128];    // 16 KB
    const int t = threadIdx.x;
    const int mat = blockIdx.x >> 8;
    const int rem = blockIdx.x & 255;
    const int row0 = (rem >> 1) << 2;
    const int colbase = (rem & 1) << 7;

    {
        int j = t >> 6, c4 = (t & 63) << 2;
        *(float4*)&xs[j][c4] = *(const float4*)&h[(mat*NN + row0 + j)*HD + c4];
    }
    __syncthreads();

    const int cg = t & 31, s = t >> 5;
    const int c0 = cg << 2;
    float4 acc[4];
    #pragma unroll
    for (int j=0;j<4;j++) acc[j] = make_float4(0.f,0.f,0.f,0.f);

    const float* wp = w2 + (s*32)*RD + colbase + c0;
    #pragma unroll 4
    for (int ii=0; ii<32; ii++){
        float4 w = *(const float4*)wp; wp += RD;
        const int i = s*32 + ii;
        #pragma unroll
        for (int j=0;j<4;j++){
            const float xv = xs[j][i];
            acc[j].x = fmaf(xv, w.x, acc[j].x);
            acc[j].y = fmaf(xv, w.y, acc[j].y);
            acc[j].z = fmaf(xv, w.z, acc[j].z);
            acc[j].w = fmaf(xv, w.w, acc[j].w);
        }
    }
    #pragma unroll
    for (int j=0;j<4;j++) *(float4*)&ps[s*4+j][c0] = acc[j];
    __syncthreads();

    float* rout = (mat==0) ? r_x : (mat==1) ? r_p : r_n;
    float* rT   = (mat==1) ? r_pT : r_nT;
    #pragma unroll
    for (int rep=0; rep<2; rep++){
        const int idx = rep*256 + t;
        const int j = idx >> 7, c = idx & 127;
        float v = 0.f;
        #pragma unroll
        for (int ss=0; ss<8; ss++) v += ps[ss*4+j][c];
        v += b2[colbase + c];
        rout[(row0+j)*RD + colbase + c] = v;
        if (mat) rT[(colbase + c)*NN + row0 + j] = v;
    }
}

// K2: A_x = r_x @ (s_w1[0:256]-s_w1[512:768]);  BT_y^T = r_y @ (s_w1[256:512]+s_w1[512:768]);
// plus squared row norms. 4 rows/block, 256 thr = 32 colgroups x 8 K-slices.
__global__ __launch_bounds__(256) void k_ab(
    const float* __restrict__ r_x, const float* __restrict__ r_p, const float* __restrict__ r_n,
    const float* __restrict__ s_w1,
    float* __restrict__ A_x, float* __restrict__ BT_p, float* __restrict__ BT_n,
    float* __restrict__ nx2, float* __restrict__ np2, float* __restrict__ nn2)
{
    __shared__ float xs[4][RD];       // 4 KB
    __shared__ float ps[32][SH];      // 16 KB
    __shared__ float red2[4][4];
    const int t = threadIdx.x;
    const int mat = blockIdx.x >> 7;
    const int row0 = (blockIdx.x & 127) << 2;
    const float* src = (mat==0) ? r_x : (mat==1) ? r_p : r_n;
    {
        int j = t >> 6, c4 = (t & 63) << 2;
        *(float4*)&xs[j][c4] = *(const float4*)&src[(row0+j)*RD + c4];
    }
    __syncthreads();

    const int cg = t & 31, s = t >> 5;
    const int c0 = cg << 2;
    float4 acc[4];
    #pragma unroll
    for (int j=0;j<4;j++) acc[j] = make_float4(0.f,0.f,0.f,0.f);

    const float sgn = (mat==0) ? -1.0f : 1.0f;
    const int base1 = (mat==0) ? 0 : 256;
    const float* p1 = s_w1 + (base1 + s*32)*SH + c0;
    const float* p3 = s_w1 + (512   + s*32)*SH + c0;
    #pragma unroll 4
    for (int ii=0; ii<32; ii++){
        float4 wa = *(const float4*)p1; p1 += SH;
        float4 wd = *(const float4*)p3; p3 += SH;
        float4 w;
        w.x = fmaf(sgn, wd.x, wa.x);
        w.y = fmaf(sgn, wd.y, wa.y);
        w.z = fmaf(sgn, wd.z, wa.z);
        w.w = fmaf(sgn, wd.w, wa.w);
        const int i = s*32 + ii;
        #pragma unroll
        for (int j=0;j<4;j++){
            const float xv = xs[j][i];
            acc[j].x = fmaf(xv, w.x, acc[j].x);
            acc[j].y = fmaf(xv, w.y, acc[j].y);
            acc[j].z = fmaf(xv, w.z, acc[j].z);
            acc[j].w = fmaf(xv, w.w, acc[j].w);
        }
    }
    #pragma unroll
    for (int j=0;j<4;j++) *(float4*)&ps[s*4+j][c0] = acc[j];
    __syncthreads();

    {
        const int c = t & 127, jb = (t >> 7) << 1;
        #pragma unroll
        for (int q=0;q<2;q++){
            const int j = jb + q;
            float v = 0.f;
            #pragma unroll
            for (int ss=0; ss<8; ss++) v += ps[ss*4+j][c];
            if (mat==0) A_x[(row0+j)*SH + c] = v;
            else ((mat==1) ? BT_p : BT_n)[c*NN + row0 + j] = v;
        }
    }

    const int lane = t & 63, wv = t >> 6;
    #pragma unroll
    for (int j=0;j<4;j++){
        float v = xs[j][t] * xs[j][t];
        #pragma unroll
        for (int off=32; off>=1; off>>=1) v += __shfl_xor(v, off);
        if (lane==0) red2[j][wv] = v;
    }
    __syncthreads();
    if (t < 4){
        float* nrm = (mat==0) ? nx2 : (mat==1) ? np2 : nn2;
        nrm[row0+t] = red2[t][0] + red2[t][1] + red2[t][2] + red2[t][3];
    }
}

// K3 (fused dist+scores+softmax): one block per (set, n). Thread t owns m=2t,2t+1.
__global__ __launch_bounds__(256) void k_sd(
    const float* __restrict__ r_x, const float* __restrict__ r_pT, const float* __restrict__ r_nT,
    const float* __restrict__ A_x, const float* __restrict__ BT_p, const float* __restrict__ BT_n,
    const float* __restrict__ nx2, const float* __restrict__ np2, const float* __restrict__ nn2,
    const float* __restrict__ s_w1, const float* __restrict__ s_b1,
    const float* __restrict__ s_w2, const float* __restrict__ s_b2,
    float* __restrict__ W_p, float* __restrict__ W_n)
{
    __shared__ float xr[RD];
    __shared__ float4 abw[SH];        // {A_x+b1, w_norm, w2, -}
    __shared__ float redm[4], reds[4];
    const int t = threadIdx.x;
    const int set = blockIdx.x >> 9;
    const int n = blockIdx.x & 511;
    const float* yT  = set ? r_nT : r_pT;
    const float* BT  = set ? BT_n : BT_p;
    const float* ny2 = set ? nn2 : np2;
    float* W = set ? W_n : W_p;

    xr[t] = r_x[n*RD + t];
    if (t < SH)
        abw[t] = make_float4(A_x[n*SH + t] + s_b1[t], s_w1[768*SH + t], s_w2[t], 0.f);
    __syncthreads();

    const int m0 = t << 1;
    // phase 1: dot(x_n, y_m) for m0, m0+1 -> distances via Gram identity
    float dx = 0.f, dy = 0.f;
    const float* yp = yT + m0;
    #pragma unroll 4
    for (int r=0; r<RD; r++){
        float2 y = *(const float2*)yp; yp += NN;
        const float xv = xr[r];
        dx = fmaf(xv, y.x, dx);
        dy = fmaf(xv, y.y, dy);
    }
    const float2 n2 = *(const float2*)&ny2[m0];
    const float nx = nx2[n];
    const float dn0 = sqrtf(fmaxf(fmaf(-2.f, dx, nx + n2.x), 0.f));
    const float dn1 = sqrtf(fmaxf(fmaf(-2.f, dy, nx + n2.y), 0.f));

    // phase 2: logits via decomposed score net
    float acc0 = 0.f, acc1 = 0.f;
    const float* bp = BT + m0;
    #pragma unroll 2
    for (int k=0; k<SH; k++){
        float2 b = *(const float2*)bp; bp += NN;
        const float4 c = abw[k];
        acc0 = fmaf(c.z, gelu_fast(fmaf(dn0, c.y, c.x + b.x)), acc0);
        acc1 = fmaf(c.z, gelu_fast(fmaf(dn1, c.y, c.x + b.y)), acc1);
    }
    const float b2v = s_b2[0];
    const float l0 = acc0 + b2v, l1 = acc1 + b2v;

    // softmax over 512 m: wave butterfly + 4-wave LDS combine
    const int lane = t & 63, wv = t >> 6;
    float vm = fmaxf(l0, l1);
    #pragma unroll
    for (int off=32; off>=1; off>>=1) vm = fmaxf(vm, __shfl_xor(vm, off));
    if (lane==0) redm[wv] = vm;
    __syncthreads();
    const float mx = fmaxf(fmaxf(redm[0], redm[1]), fmaxf(redm[2], redm[3]));
    const float e0 = __builtin_amdgcn_exp2f((l0 - mx) * 1.4426950408889634f);
    const float e1 = __builtin_amdgcn_exp2f((l1 - mx) * 1.4426950408889634f);
    float vs = e0 + e1;
    #pragma unroll
    for (int off=32; off>=1; off>>=1) vs += __shfl_xor(vs, off);
    if (lane==0) reds[wv] = vs;
    __syncthreads();
    const float inv = __builtin_amdgcn_rcpf(reds[0] + reds[1] + reds[2] + reds[3]);
    *(float2*)&W[n*NN + m0] = make_float2(e0*inv, e1*inv);
}

// K4: out[n] = (W_p[n]@r_p - W_n[n]@r_n) @ out_w   (x_rep term cancels pos-neg).
__global__ __launch_bounds__(512) void k_final(
    const float* __restrict__ W_p, const float* __restrict__ W_n,
    const float* __restrict__ r_p, const float* __restrict__ r_n,
    const float* __restrict__ out_w, float* __restrict__ out)
{
    __shared__ float wp[2][NN];
    __shared__ float wq[2][NN];
    __shared__ float psA[16][RD];
    __shared__ float dv[2][RD];
    __shared__ float ps2[8][NN];
    const int t = threadIdx.x;
    const int n0 = blockIdx.x << 1;

    {
        const int j = (t >> 7) & 1, c4 = (t & 127) << 2;
        if (t < 256) *(float4*)&wp[j][c4] = *(const float4*)&W_p[(n0+j)*NN + c4];
        else         *(float4*)&wq[j][c4] = *(const float4*)&W_n[(n0+j)*NN + c4];
    }
    __syncthreads();

    {
        const int cg = t & 63, s = t >> 6;
        const int c0 = cg << 2;
        float4 a0 = make_float4(0.f,0.f,0.f,0.f), a1 = a0;
        const float* pp = r_p + (s*64)*RD + c0;
        const float* pn = r_n + (s*64)*RD + c0;
        #pragma unroll 4
        for (int mm=0; mm<64; mm++){
            float4 yp4 = *(const float4*)pp; pp += RD;
            float4 yn4 = *(const float4*)pn; pn += RD;
            const int m = s*64 + mm;
            const float w0 = wp[0][m], w1v = wp[1][m];
            const float q0 = wq[0][m], q1v = wq[1][m];
            a0.x = fmaf(w0, yp4.x, a0.x); a0.x = fmaf(-q0, yn4.x, a0.x);
            a0.y = fmaf(w0, yp4.y, a0.y); a0.y = fmaf(-q0, yn4.y, a0.y);
            a0.z = fmaf(w0, yp4.z, a0.z); a0.z = fmaf(-q0, yn4.z, a0.z);
            a0.w = fmaf(w0, yp4.w, a0.w); a0.w = fmaf(-q0, yn4.w, a0.w);
            a1.x = fmaf(w1v, yp4.x, a1.x); a1.x = fmaf(-q1v, yn4.x, a1.x);
            a1.y = fmaf(w1v, yp4.y, a1.y); a1.y = fmaf(-q1v, yn4.y, a1.y);
            a1.z = fmaf(w1v, yp4.z, a1.z); a1.z = fmaf(-q1v, yn4.z, a1.z);
            a1.w = fmaf(w1v, yp4.w, a1.w); a1.w = fmaf(-q1v, yn4.w, a1.w);
        }
        *(float4*)&psA[s*2+0][c0] = a0;
        *(float4*)&psA[s*2+1][c0] = a1;
    }
    __syncthreads();

    {
        const int j = t >> 8, c = t & 255;
        float v = 0.f;
        #pragma unroll
        for (int ss=0; ss<8; ss++) v += psA[ss*2+j][c];
        dv[j][c] = v;
    }
    __syncthreads();

    {
        const int og = t & 127, s = t >> 7;
        const int c0 = og << 2;
        float4 a0 = make_float4(0.f,0.f,0.f,0.f), a1 = a0;
        const float* wo = out_w + (s*64)*IN + c0;
        #pragma unroll 4
        for (int rr=0; rr<64; rr++){
            float4 w = *(const float4*)wo; wo += IN;
            const int r = s*64 + rr;
            const float d0 = dv[0][r], d1 = dv[1][r];
            a0.x = fmaf(d0, w.x, a0.x); a0.y = fmaf(d0, w.y, a0.y);
            a0.z = fmaf(d0, w.z, a0.z); a0.w = fmaf(d0, w.w, a0.w);
            a1.x = fmaf(d1, w.x, a1.x); a1.y = fmaf(d1, w.y, a1.y);
            a1.z = fmaf(d1, w.z, a1.z); a1.w = fmaf(d1, w.w, a1.w);
        }
        *(float4*)&ps2[s*2+0][c0] = a0;
        *(float4*)&ps2[s*2+1][c0] = a1;
    }
    __syncthreads();

    {
        const int c = t;
        #pragma unroll
        for (int j=0;j<2;j++){
            float v = 0.f;
            #pragma unroll
            for (int ss=0; ss<4; ss++) v += ps2[ss*2+j][c];
            out[(n0+j)*IN + c] = v;
        }
    }
}

extern "C" void kernel_launch(void* const* d_in, const int* in_sizes, int n_in,
                              void* d_out, int out_size, void* d_ws, size_t ws_size,
                              hipStream_t stream)
{
    const float* fx  = (const float*)d_in[0];
    const float* fp  = (const float*)d_in[1];
    const float* fn  = (const float*)d_in[2];
    const float* gw1 = (const float*)d_in[3];
    const float* gb1 = (const float*)d_in[4];
    const float* gw2 = (const float*)d_in[5];
    const float* gb2 = (const float*)d_in[6];
    const float* ow  = (const float*)d_in[7];
    const float* sw1 = (const float*)d_in[8];
    const float* sb1 = (const float*)d_in[9];
    const float* sw2 = (const float*)d_in[10];
    const float* sb2 = (const float*)d_in[11];
    float* out = (float*)d_out;

    float* ws   = (float*)d_ws;
    float* r_x  = ws;               // 512*256
    float* r_p  = r_x  + 131072;
    float* r_n  = r_p  + 131072;
    float* r_pT = r_n  + 131072;    // 256*512
    float* r_nT = r_pT + 131072;
    float* A_x  = r_nT + 131072;    // 512*128
    float* BT_p = A_x  + 65536;     // 128*512
    float* BT_n = BT_p + 65536;
    float* nx2  = BT_n + 65536;     // 512
    float* np2  = nx2  + 512;
    float* nn2  = np2  + 512;
    float* W_p  = nn2  + 512;       // 512*512
    float* W_n  = W_p  + 262144;
    float* hbuf = W_n  + 262144;    // 1536*256

    hipLaunchKernelGGL(k_g1, dim3(768), dim3(256), 0, stream,
                       fx, fp, fn, gw1, gb1, hbuf);
    hipLaunchKernelGGL(k_g2, dim3(768), dim3(256), 0, stream,
                       hbuf, gw2, gb2, r_x, r_p, r_n, r_pT, r_nT);
    hipLaunchKernelGGL(k_ab, dim3(384), dim3(256), 0, stream,
                       r_x, r_p, r_n, sw1, A_x, BT_p, BT_n, nx2, np2, nn2);
    hipLaunchKernelGGL(k_sd, dim3(1024), dim3(256), 0, stream,
                       r_x, r_pT, r_nT, A_x, BT_p, BT_n, nx2, np2, nn2,
                       sw1, sb1, sw2, sb2, W_p, W_n);
    hipLaunchKernelGGL(k_final, dim3(256), dim3(512), 0, stream,
                       W_p, W_n, r_p, r_n, ow, out);
}